// Round 13
// baseline (364.712 us; speedup 1.0000x reference)
//
#include <hip/hip_runtime.h>
#include <math.h>

#define HH 1024
#define WW 1024
#define NPLANES 12              // B*C = 4*3
#define PLANE (HH * WW)

#define TW 64                   // output tile width
#define TH 64                   // output tile height
#define RH 92                   // h1 rows: gy in [y0-14, y0+77]  (phys rows 0..91)
#define RB 78                   // B1/h2 logical rows: gy in [y0-7, y0+70]
#define PH 80                   // H pitch (floats), 20 quads
// LDS map (floats):
//   [0      .. 7359 ]  H     : h1 rows 0..91 (pitch 80); later h2 in rows 0..77
//   [7360   .. 12479]  B1    : logical rows 0..63 at phys 92..155 (pitch 80);
//                              logical rows 64..77 ALIAS H phys rows 78..91
//   [7360   .. 11775]  A     : 46 x 96 chained-input staging (two passes);
//                              dead before P3 writes B1 (barrier-separated).
#define AOFF 7360
#define APITCH 96               // 24 quads = 3 FULL 8-quad groups
#define LDSF (156 * PH)         // 49,920 B -> 50,176 alloc -> 3 blocks/CU @512thr

struct W15 { float w[15]; };

// ---- H swizzle (pitch 20 quads, PARTIAL last group): 2-bit XOR within aligned
// 4-quad groups — in-range by construction.
__device__ inline int swq(int pr, int q) { return pr * PH + ((q ^ (pr & 3)) << 2); }
__device__ inline int sws(int pr, int j) {
    return pr * PH + ((((j >> 2) ^ (pr & 3)) << 2) | (j & 3));
}
// ---- A swizzle (pitch 24 quads = 3 FULL groups): 3-bit XOR within groups —
// in-range & bijective (R9-verified). Conflict spread across lanes is provided
// by ISSUE-ORDER ROTATION in the readers/writers, not by the layout.
__device__ inline int aq(int r, int q) {
    return AOFF + r * APITCH + (((q & 24) | ((q ^ r) & 7)) << 2);
}
__device__ inline int as(int r, int c) {
    int q = c >> 2;
    return AOFF + r * APITCH + ((((q & 24) | ((q ^ r) & 7)) << 2) | (c & 3));
}
// B1 logical row -> physical LDS row
__device__ inline int b1r(int r) { return (r < 64) ? (92 + r) : (r + 14); }

// pointwise chain with pre-folded constants:
//   k2 = sb+hr ; kc = 0.5 + br - 0.5*ct
__device__ inline float chain1(float t, float gain, float gamma, float sb,
                               float k2, float ct, float kc) {
    t = t * gain;
    t = __builtin_amdgcn_exp2f(gamma * __log2f(t));          // pow(t,gamma), t>=0
    float hi = __fdividef(1.0f, 1.0f + __expf((0.5f - t) * 10.0f));
    t = fmaf(-k2, hi, t + sb);                               // t + sb*(1-hi) - hr*hi
    t = fminf(fmaxf(t, 0.0f), 1.0f);
    t = fmaf(ct, t, kc);                                     // ct*(t-0.5)+0.5+br
    return fminf(fmaxf(t, 0.0f), 1.0f);
}

// 16 outputs from a 32-float register window; output j taps f[j+1 .. j+15]
__device__ inline void dot16(const float* f, const W15& wk, float* o) {
#pragma unroll
    for (int j = 0; j < 16; ++j) {
        float a = 0.0f, b = 0.0f;
#pragma unroll
        for (int k = 0; k < 8; ++k)  a += wk.w[k] * f[j + 1 + k];
#pragma unroll
        for (int k = 8; k < 15; ++k) b += wk.w[k] * f[j + 1 + k];
        o[j] = a + b;
    }
}

// ---- XCD-aware tile remap: same-XCD (mod-8) blocks cover contiguous region ---
__device__ inline void tile_map(int& p, int& x0, int& y0, bool& edge) {
    int L = (blockIdx.z * gridDim.y + blockIdx.y) * gridDim.x + blockIdx.x; // 0..3071
    int xcd = L & 7;
    int t   = L >> 3;
    int g   = xcd * 384 + t;          // contiguous 1.5-plane region per XCD
    p = g >> 8;
    int w  = g & 255;
    int ty = w >> 4, tx = w & 15;
    x0 = tx * TW; y0 = ty * TH;
    edge = (tx == 0) || (tx == 15) || (ty == 0) || (ty == 15);
}

// P0: chain(x) for one 46-row vertical half into A (zero outside image)
__device__ inline void stage_A(float* lds, const float* __restrict__ plane,
                               int x0, int gyb, bool edge, int tid,
                               float gain, float gamma, float sb,
                               float k2, float ct, float kc) {
#pragma unroll
    for (int k = 0; k < 2; ++k) {
        int u = tid + 512 * k;                   // < 1024 < 1104, always active
        int r = u / 24, q = u - 24 * r;
        int gy = gyb + r;
        int gq = x0 - 16 + 4 * q;                // 4-aligned: quad all-in/all-out
        float4 v = make_float4(0.f, 0.f, 0.f, 0.f);
        if (!edge || ((unsigned)gy < HH && gq >= 0 && gq + 3 < WW)) {
            v = *(const float4*)(plane + (size_t)gy * WW + gq);
            float* pv = (float*)&v;
#pragma unroll
            for (int j = 0; j < 4; ++j)
                pv[j] = chain1(pv[j], gain, gamma, sb, k2, ct, kc);
        }
        *(float4*)&lds[aq(r, q)] = v;
    }
    if (tid < 46 * 24 - 1024) {                  // tail: 80 threads
        int u = tid + 1024;
        int r = u / 24, q = u - 24 * r;
        int gy = gyb + r;
        int gq = x0 - 16 + 4 * q;
        float4 v = make_float4(0.f, 0.f, 0.f, 0.f);
        if (!edge || ((unsigned)gy < HH && gq >= 0 && gq + 3 < WW)) {
            v = *(const float4*)(plane + (size_t)gy * WW + gq);
            float* pv = (float*)&v;
#pragma unroll
            for (int j = 0; j < 4; ++j)
                pv[j] = chain1(pv[j], gain, gamma, sb, k2, ct, kc);
        }
        *(float4*)&lds[aq(r, q)] = v;
    }
}

// P1: h1 rows (one 46-row half) from A. Issue-order rotation: read i2=(i+3s)&7,
// write q2=(qq+s)&3 -> per-instruction lane quad-sets hit 4-5 distinct
// quad-banks instead of 2 (stride-4 residue collapse).
__device__ inline void hblur_half(float* lds, int hrow0, int tid, const W15& wk) {
    if (tid < 46 * 5) {
        int r = tid / 5, s = tid - 5 * r;        // A row r, out cols 16s..16s+15
        float f[32];
#pragma unroll
        for (int i = 0; i < 8; ++i) {
            int i2 = (i + 3 * s) & 7;
            *(float4*)&f[4 * i2] = *(const float4*)&lds[aq(r, 4 * s + i2)];
        }
        float o[16];
        dot16(f, wk, o);
        int hr_ = hrow0 + r;
#pragma unroll
        for (int qq = 0; qq < 4; ++qq) {
            int q2 = (qq + s) & 3;
            *(float4*)&lds[swq(hr_, 4 * s + q2)] = *(float4*)&o[4 * q2];
        }
    }
}

// =============================================================================
// Fully fused single kernel (512 threads, 64x64 tile, 3 blocks/CU):
//  P0a: chain(x) rows y0-14..y0+31 -> A      | bar
//  P1a: h1 rows 0..45 = hblur(A); cc for ty<4 from A | bar
//  P0b: chain(x) rows y0+32..y0+77 -> A      | bar
//  P1b: h1 rows 46..91; cc for ty>=4 from A  | bar
//  P3 : B1 = vblur(h1) masked to image (5 bands; band 4 owns aliased rows) | bar
//  bb : B1 centers -> regs (phys rows 78..155, disjoint from P4 writes 0..77)
//  P4 : h2 = hblur(B1) -> H rows 0..77 (issue-order rotated) | bar
//  P5 : B2 = vblur(h2); x2c=(1+e)cc-e*bb; bx2=(1+e)bb-e*B2;
//       out = clip((s*bx2+(1-s)*x2c)*(1-intensity*mask)), NT store
// =============================================================================
__global__ __launch_bounds__(512, 6) void k_fused(
    const float* __restrict__ x, float* __restrict__ dst,
    const float* __restrict__ gains,
    const float* __restrict__ pg, const float* __restrict__ psb,
    const float* __restrict__ phr, const float* __restrict__ pbr,
    const float* __restrict__ pct, const float* __restrict__ penh,
    const float* __restrict__ psoft, const float* __restrict__ pint,
    const float* __restrict__ prot, const float* __restrict__ phard,
    W15 wk)
{
    __shared__ float lds[LDSF];

    int p, x0, y0; bool edge;
    tile_map(p, x0, y0, edge);
    const int tid = threadIdx.x;
    const int tx  = tid & 63;
    const int ty  = tid >> 6;            // 0..7

    const float* __restrict__ plane = x + (size_t)p * PLANE;
    const float gain  = gains[p % 3];
    const float gamma = *pg, sb = *psb, hrp = *phr, br = *pbr, ct = *pct;
    const float k2 = sb + hrp;
    const float kc = 0.5f + br - 0.5f * ct;

    float cc[8];

    // ---------------- P0a / P1a (+cc rows 0..31) ------------------------------
    stage_A(lds, plane, x0, y0 - 14, edge, tid, gain, gamma, sb, k2, ct, kc);
    __syncthreads();
    hblur_half(lds, 0, tid, wk);
    if (ty < 4) {                        // centers gy = y0 + ty*8 + jj, A row +14
#pragma unroll
        for (int jj = 0; jj < 8; ++jj)
            cc[jj] = lds[as(ty * 8 + jj + 14, tx + 16)];
    }
    __syncthreads();

    // ---------------- P0b / P1b (+cc rows 32..63) -----------------------------
    stage_A(lds, plane, x0, y0 + 32, edge, tid, gain, gamma, sb, k2, ct, kc);
    __syncthreads();
    hblur_half(lds, 46, tid, wk);
    if (ty >= 4) {                       // A row = ty*8 + jj + 14 - 46
#pragma unroll
        for (int jj = 0; jj < 8; ++jj)
            cc[jj] = lds[as(ty * 8 + jj - 32, tx + 16)];
    }
    __syncthreads();

    // ---------------- P3: B1 = vblur(h1), masked to image support -------------
    // bands {16,16,16,16,14}: bands 0..3 cover rl 0..63 (write phys 92..155,
    // read rows <= 77); band 4 covers rl 64..77 (reads rows 64..91; each write
    // to phys rl+14 follows this thread's read of that same row/col).
    if (tid < 400) {
        int j = tid % 80, band = tid / 80;
        int rb0 = band * 16;                 // 0,16,32,48,64
        int nb  = (band == 4) ? 14 : 16;
        bool xin = (unsigned)(x0 - 8 + j) < WW;
        float win[15];
#pragma unroll
        for (int k = 0; k < 14; ++k) win[k] = lds[sws(rb0 + k, j)];
#pragma unroll
        for (int jj = 0; jj < 16; ++jj) {
            if (jj < nb) {
                win[(jj + 14) % 15] = lds[sws(rb0 + jj + 14, j)];
                float a = 0.0f, b = 0.0f;
#pragma unroll
                for (int k = 0; k < 8; ++k)  a += wk.w[k] * win[(jj + k) % 15];
#pragma unroll
                for (int k = 8; k < 15; ++k) b += wk.w[k] * win[(jj + k) % 15];
                float v = a + b;
                if (edge) {
                    int gy = y0 - 7 + rb0 + jj;
                    if (!((unsigned)gy < HH) || !xin) v = 0.0f;
                }
                lds[sws(b1r(rb0 + jj), j)] = v;
            }
        }
    }
    __syncthreads();

    // ---------------- bb: B1 centers -> regs (overlaps P4; disjoint rows) -----
    const int ry0 = ty * 8;
    float bb[8];
#pragma unroll
    for (int jj = 0; jj < 8; ++jj)
        bb[jj] = lds[sws(b1r(ry0 + jj + 7), tx + 8)];   // phys 78..84 / 99..155

    // ---------------- P4: h2 = hblur(B1) -> rows 0..77 (writes phys 0..77) ----
    if (tid < RB * 4) {
        int rb = tid >> 2, s = tid & 3;      // out cols gx = x0 + 16s + j
        int pb = b1r(rb);
        float f[32];
#pragma unroll
        for (int i = 0; i < 8; ++i) {
            int i2 = (i + 3 * s) & 7;
            *(float4*)&f[4 * i2] = *(const float4*)&lds[swq(pb, 4 * s + i2)];
        }
        float o[16];
        dot16(f, wk, o);
#pragma unroll
        for (int qq = 0; qq < 4; ++qq) {
            int q2 = (qq + s) & 3;
            *(float4*)&lds[swq(rb, 4 * s + q2)] = *(float4*)&o[4 * q2];
        }
    }
    __syncthreads();

    // ---------------- P5: B2 = vblur(h2); combine + mask + clip + store -------
    const float e     = *penh;
    const float sf    = *psoft;
    const float inten = *pint;
    const float hard  = *phard;
    const float theta = (*prot) * 0.017453292519943295f;
    const float cth = __cosf(theta), sth = __sinf(theta);
    const int   gx    = x0 + tx;
    const float gbase = (-1.0f + 2.0f * (float)gx * (1.0f / (float)(WW - 1))) * cth;
    const float ce    = 1.0f + e;

    // gradient-mask exp is linear in y -> geometric recurrence (1 exp, 7 muls)
    const float dstep = 2.0f / (float)(HH - 1);
    const float gy0n  = -1.0f + (float)(y0 + ry0) * dstep;
    float       E     = __expf(hard * (gbase + gy0n * sth));
    const float q     = __expf(hard * sth * dstep);

    float win[15];
#pragma unroll
    for (int k = 0; k < 14; ++k) win[k] = lds[sws(ry0 + k, tx)];

    float* __restrict__ dstP = dst + (size_t)p * PLANE;
#pragma unroll
    for (int jj = 0; jj < 8; ++jj) {
        win[(jj + 14) % 15] = lds[sws(ry0 + jj + 14, tx)];
        float a = 0.0f, b = 0.0f;
#pragma unroll
        for (int k = 0; k < 8; ++k)  a += wk.w[k] * win[(jj + k) % 15];
#pragma unroll
        for (int k = 8; k < 15; ++k) b += wk.w[k] * win[(jj + k) % 15];
        float B2  = a + b;
        float x2c = ce * cc[jj] - e * bb[jj];       // x2 at center
        float bx2 = ce * bb[jj] - e * B2;           // blur(x2) via linearity
        float v   = sf * bx2 + (1.0f - sf) * x2c;
        int   y   = y0 + ry0 + jj;
        float mask = __fdividef(1.0f, 1.0f + E);
        E *= q;
        v = v * (1.0f - inten * mask);
        v = fminf(fmaxf(v, 0.0f), 1.0f);
        __builtin_nontemporal_store(v, &dstP[(size_t)y * WW + gx]);
    }
}

extern "C" void kernel_launch(void* const* d_in, const int* in_sizes, int n_in,
                              void* d_out, int out_size, void* d_ws, size_t ws_size,
                              hipStream_t stream)
{
    const float* x       = (const float*)d_in[0];
    const float* gains   = (const float*)d_in[1];
    const float* p_gamma = (const float*)d_in[2];
    const float* p_sb    = (const float*)d_in[3];
    const float* p_hr    = (const float*)d_in[4];
    const float* p_br    = (const float*)d_in[5];
    const float* p_ct    = (const float*)d_in[6];
    const float* p_enh   = (const float*)d_in[7];
    const float* p_soft  = (const float*)d_in[8];
    const float* p_int   = (const float*)d_in[9];
    const float* p_rot   = (const float*)d_in[10];
    const float* p_hard  = (const float*)d_in[11];

    W15 wk;
    {
        double g[15], sum = 0.0;
        for (int i = 0; i < 15; ++i) { double d = (double)(i - 7); g[i] = exp(-d * d / 18.0); sum += g[i]; }
        for (int i = 0; i < 15; ++i) wk.w[i] = (float)(g[i] / sum);
    }

    // Single fused kernel: x -> out (no workspace -> no ws-poison overhead)
    dim3 grid(WW / TW, HH / TH, NPLANES);   // 16 x 16 x 12 (remapped in-kernel)
    k_fused<<<grid, dim3(512), 0, stream>>>(
        x, (float*)d_out, gains, p_gamma, p_sb, p_hr, p_br, p_ct,
        p_enh, p_soft, p_int, p_rot, p_hard, wk);
}